// Round 6
// baseline (836.969 us; speedup 1.0000x reference)
//
#include <hip/hip_runtime.h>

// Shapes (fixed): B=4, N=256, F=6, H=128, D=256, B*N=1024
// out = concat(adj_pred [4,256,256], feat_pred [4,256,6]) written as fp32.
// Inputs may be fp32 or bf16 -- detected on device, converted to fp32 in ws.

__device__ __forceinline__ float b2f(unsigned short h) {
    union { unsigned int u; float f; } v;
    v.u = ((unsigned int)h) << 16;
    return v.f;
}

// ---- dtype detector: fp32 data read as ushort has random low halves ->
// exponent bits (14..7) == 0xFF occurs ~1/256; true bf16 never does. ----
__global__ void k_detect(const unsigned short* x, int nx,
                         const unsigned short* w, int nw, int* flag) {
    __shared__ int cnt[256];
    int t = threadIdx.x;
    int c = 0;
    for (int i = t; i < nx; i += 256) { if (((x[i] >> 7) & 0xFF) == 0xFF) c++; }
    for (int i = t; i < nw; i += 256) { if (((w[i] >> 7) & 0xFF) == 0xFF) c++; }
    cnt[t] = c;
    __syncthreads();
    for (int o = 128; o > 0; o >>= 1) {
        if (t < o) cnt[t] += cnt[t + o];
        __syncthreads();
    }
    if (t == 0) flag[0] = (cnt[0] > 0) ? 1 : 0;   // 1 => inputs are fp32
}

// ---- convert any input to fp32 scratch ----
__global__ void k_conv(const void* src, float* dst, int n, const int* flag) {
    int i = blockIdx.x * 256 + threadIdx.x;
    if (i >= n) return;
    if (flag[0]) dst[i] = ((const float*)src)[i];
    else         dst[i] = b2f(((const unsigned short*)src)[i]);
}

// dg[row] = rsqrt(max(rowsum(adj)+1, 1)), row in [0,1024)
__global__ void k_deg(const float* adj, float* dg) {
    int row = blockIdx.x * 256 + threadIdx.x;
    if (row < 1024) {
        const float* ap = adj + row * 256;
        float s = 0.f;
        for (int j = 0; j < 256; j++) s += ap[j];
        s = s + 1.f;
        if (s < 1.f) s = 1.f;
        dg[row] = rsqrtf(s);
    }
}

// An[b,i,j] = d_i * (adj[b,i,j] + I) * d_j
__global__ void k_an(const float* adj, const float* dg, float* An) {
    int idx = blockIdx.x * 256 + threadIdx.x;   // 262144
    int b = idx >> 16, i = (idx >> 8) & 255, j = idx & 255;
    float v = adj[idx] + ((i == j) ? 1.f : 0.f);
    An[idx] = dg[b * 256 + i] * v * dg[b * 256 + j];
}

// C(MxN) = A(MxK) @ B(KxN) [+bias][relu], all fp32
__global__ void k_mm(const float* A, const float* B, const float* bias,
                     float* C, int M, int K, int N, int relu) {
    int idx = blockIdx.x * 256 + threadIdx.x;
    if (idx >= M * N) return;
    int n = idx % N, m = idx / N;
    float s = (bias != 0) ? bias[n] : 0.f;
    for (int k = 0; k < K; k++) s += A[m * K + k] * B[k * N + n];
    if (relu && s < 0.f) s = 0.f;
    C[idx] = s;
}

// batched: C[b](MxN) = A[b](MxK) @ B[b](KxN) [+bias][relu]
__global__ void k_mmb(const float* A, const float* B, const float* bias,
                      float* C, int M, int K, int N, int relu,
                      int sA, int sB, int sC, int total) {
    int idx = blockIdx.x * 256 + threadIdx.x;
    if (idx >= total) return;
    int per = M * N;
    int b = idx / per;
    int r = idx - b * per;
    int n = r % N, m = r / N;
    const float* Ab = A + b * sA;
    const float* Bb = B + b * sB;
    float s = (bias != 0) ? bias[n] : 0.f;
    for (int k = 0; k < K; k++) s += Ab[m * K + k] * Bb[k * N + n];
    if (relu && s < 0.f) s = 0.f;
    C[b * sC + r] = s;
}

// BatchNorm stats over (1024,128): st[c]=mu, st[128+c]=rstd
__global__ void k_bn_stats(const float* pre, float* st) {
    __shared__ float ss[256];
    __shared__ float qq[256];
    int c = blockIdx.x;        // 128 blocks
    int t = threadIdx.x;
    float s = 0.f, q = 0.f;
    for (int r = t; r < 1024; r += 256) {
        float v = pre[r * 128 + c];
        s += v; q += v * v;
    }
    ss[t] = s; qq[t] = q;
    __syncthreads();
    for (int o = 128; o > 0; o >>= 1) {
        if (t < o) { ss[t] += ss[t + o]; qq[t] += qq[t + o]; }
        __syncthreads();
    }
    if (t == 0) {
        float mu  = ss[0] * (1.f / 1024.f);
        float var = qq[0] * (1.f / 1024.f) - mu * mu;
        st[c] = mu;
        st[128 + c] = rsqrtf(var + 1e-5f);
    }
}

__global__ void k_bn_apply(const float* pre, float* o, const float* st,
                           const float* g, const float* beta) {
    int i = blockIdx.x * 256 + threadIdx.x;     // 131072
    int c = i & 127;
    float v = (pre[i] - st[c]) * st[128 + c] * g[c] + beta[c];
    if (v < 0.f) v = 0.f;
    o[i] = v;
}

// pairwise decoder: logit[b,i,j] = relu(relu(hi[b,i]+hj[b,j]+e1b) @ e2w + e2b) @ e3w + e3b
// block = (b,i) [1024 blocks], thread = j [256]
__global__ void k_dec(const float* hi, const float* hj, const float* e1b,
                      const float* e2w, const float* e2b,
                      const float* e3w, const float* e3b, float* lgt) {
    __shared__ float Ws[8192];     // e2w [k*64+n]
    __shared__ float pre[128];     // hi[b,i] + e1b
    __shared__ float e2bs[64];
    __shared__ float e3ws[64];
    int tid = threadIdx.x;
    int bi = blockIdx.x, b = bi >> 8;
    for (int s = tid; s < 8192; s += 256) Ws[s] = e2w[s];
    if (tid < 128) {
        pre[tid] = hi[bi * 128 + tid] + e1b[tid];
    } else if (tid < 192) {
        e2bs[tid - 128] = e2b[tid - 128];
        e3ws[tid - 128] = e3w[tid - 128];
    }
    __syncthreads();
    const float* hrow = hj + (b * 256 + tid) * 128;
    float acc[64];
    #pragma unroll
    for (int n = 0; n < 64; n++) acc[n] = 0.f;
    for (int k = 0; k < 128; k++) {
        float p = pre[k] + hrow[k];
        if (p < 0.f) p = 0.f;
        const float* w = Ws + k * 64;
        #pragma unroll
        for (int n = 0; n < 64; n++) acc[n] += p * w[n];
    }
    float s = e3b[0];
    #pragma unroll
    for (int n = 0; n < 64; n++) {
        float v = acc[n] + e2bs[n];
        if (v < 0.f) v = 0.f;
        s += v * e3ws[n];
    }
    lgt[bi * 256 + tid] = s;
}

// out[idx] = sigmoid(0.5*(lg[b,i,j] + lg[b,j,i])) as fp32
__global__ void k_symsig(const float* lgt, float* out) {
    int idx = blockIdx.x * 256 + threadIdx.x;   // 262144
    int b = idx >> 16, i = (idx >> 8) & 255, j = idx & 255;
    float v = 0.5f * (lgt[idx] + lgt[(b << 16) + (j << 8) + i]);
    out[idx] = 1.f / (1.f + expf(-v));
}

// feat decoder last layer: (1024x128)@(128x6)+b -> fp32
__global__ void k_f3(const float* f2, const float* w, const float* bias,
                     float* out) {
    int idx = blockIdx.x * 256 + threadIdx.x;   // 6144
    if (idx >= 6144) return;
    int r = idx / 6, c = idx % 6;
    float s = bias[c];
    for (int k = 0; k < 128; k++) s += f2[r * 128 + k] * w[k * 6 + c];
    out[idx] = s;
}

extern "C" void kernel_launch(void* const* d_in, const int* in_sizes, int n_in,
                              void* d_out, int out_size, void* d_ws, size_t ws_size,
                              hipStream_t stream) {
    float* out = (float*)d_out;

    // workspace budget: converted inputs (~443K) + work buffers (~1574K) + flag
    if (ws_size < (size_t)2100000 * 4) {
        hipMemsetAsync(d_out, 0x60, 4096, stream);   // diagnostic: ws too small
        return;
    }

    float* cur = (float*)d_ws;
    // converted inputs (fp32), in d_in order
    float* ci[24];
    for (int i = 0; i < 24; i++) {
        ci[i] = cur;
        int n = in_sizes[i];
        int np = (n + 3) & ~3;      // keep 16B alignment
        cur += np;
    }
    // work buffers
    float* An  = cur; cur += 262144;
    float* buf = cur; cur += 262144;
    float* hb  = cur; cur += 262144;
    float* lg  = cur; cur += 262144;
    float* h1  = cur; cur += 131072;
    float* h2  = cur; cur += 131072;
    float* hi  = cur; cur += 131072;
    float* hj  = cur; cur += 131072;
    float* st  = cur; cur += 256;
    float* dg  = cur; cur += 1024;
    int*   flag = (int*)cur; cur += 4;

    // 1) detect input dtype from x (Gaussian) + e1w (large Gaussian)
    k_detect<<<1, 256, 0, stream>>>((const unsigned short*)d_in[0], in_sizes[0],
                                    (const unsigned short*)d_in[12], in_sizes[12],
                                    flag);
    // 2) convert all inputs to fp32
    for (int i = 0; i < 24; i++) {
        int n = in_sizes[i];
        int g = (n + 255) / 256;
        if (g < 1) g = 1;
        k_conv<<<g, 256, 0, stream>>>(d_in[i], ci[i], n, flag);
    }

    const float* x   = ci[0];
    const float* adj = ci[1];
    const float* W1  = ci[2];  const float* b1  = ci[3];
    const float* W2  = ci[4];  const float* b2  = ci[5];
    const float* W3  = ci[6];  const float* b3  = ci[7];
    const float* g1  = ci[8];  const float* be1 = ci[9];
    const float* g2  = ci[10]; const float* be2 = ci[11];
    const float* e1w = ci[12]; const float* e1b = ci[13];
    const float* e2w = ci[14]; const float* e2b = ci[15];
    const float* e3w = ci[16]; const float* e3b = ci[17];
    const float* f1w = ci[18]; const float* f1b = ci[19];
    const float* f2w = ci[20]; const float* f2b_ = ci[21];
    const float* f3w = ci[22]; const float* f3b = ci[23];

    k_deg<<<4, 256, 0, stream>>>(adj, dg);
    k_an<<<1024, 256, 0, stream>>>(adj, dg, An);

    // layer 1: buf = x@W1 ; h1 = An@buf + b1 ; BN ; relu
    k_mm<<<512, 256, 0, stream>>>(x, W1, 0, buf, 1024, 6, 128, 0);
    k_mmb<<<512, 256, 0, stream>>>(An, buf, b1, h1, 256, 256, 128, 0,
                                   65536, 32768, 32768, 131072);
    k_bn_stats<<<128, 256, 0, stream>>>(h1, st);
    k_bn_apply<<<512, 256, 0, stream>>>(h1, h1, st, g1, be1);

    // layer 2
    k_mm<<<512, 256, 0, stream>>>(h1, W2, 0, buf, 1024, 128, 128, 0);
    k_mmb<<<512, 256, 0, stream>>>(An, buf, b2, h2, 256, 256, 128, 0,
                                   65536, 32768, 32768, 131072);
    k_bn_stats<<<128, 256, 0, stream>>>(h2, st);
    k_bn_apply<<<512, 256, 0, stream>>>(h2, h2, st, g2, be2);

    // layer 3: hb = relu(An@(h2@W3) + b3)
    k_mm<<<1024, 256, 0, stream>>>(h2, W3, 0, buf, 1024, 128, 256, 0);
    k_mmb<<<1024, 256, 0, stream>>>(An, buf, b3, hb, 256, 256, 256, 1,
                                    65536, 65536, 65536, 262144);

    // adjacency decoder: hi = hb@e1w[:256], hj = hb@e1w[256:]
    k_mm<<<512, 256, 0, stream>>>(hb, e1w, 0, hi, 1024, 256, 128, 0);
    k_mm<<<512, 256, 0, stream>>>(hb, e1w + 256 * 128, 0, hj, 1024, 256, 128, 0);
    k_dec<<<1024, 256, 0, stream>>>(hi, hj, e1b, e2w, e2b, e3w, e3b, lg);
    k_symsig<<<1024, 256, 0, stream>>>(lg, out);

    // feature decoder (reuse h1/h2)
    k_mm<<<512, 256, 0, stream>>>(hb, f1w, f1b, h1, 1024, 256, 128, 1);
    k_mm<<<512, 256, 0, stream>>>(h1, f2w, f2b_, h2, 1024, 128, 128, 1);
    k_f3<<<24, 256, 0, stream>>>(h2, f3w, f3b, out + 262144);
}

// Round 7
// 347.473 us; speedup vs baseline: 2.4087x; 2.4087x over previous
//
#include <hip/hip_runtime.h>

// Shapes (fixed): B=4, N=256, F=6, H=128, D=256, B*N=1024
// All tensors fp32. out = concat(adj_pred [4,256,256], feat_pred [4,256,6]).

// ---- degree: block per row, LDS tree reduction ----
__global__ void k_deg(const float* adj, float* dg) {
    __shared__ float ss[256];
    int row = blockIdx.x;            // 1024
    int t = threadIdx.x;
    ss[t] = adj[row * 256 + t];
    __syncthreads();
    for (int o = 128; o > 0; o >>= 1) {
        if (t < o) ss[t] += ss[t + o];
        __syncthreads();
    }
    if (t == 0) {
        float s = ss[0] + 1.f;
        if (s < 1.f) s = 1.f;
        dg[row] = rsqrtf(s);
    }
}

// ---- An[b,i,j] = d_i * (adj + I) * d_j ----
__global__ void k_an(const float* adj, const float* dg, float* An) {
    int idx = blockIdx.x * 256 + threadIdx.x;   // 262144
    int b = idx >> 16, i = (idx >> 8) & 255, j = idx & 255;
    float v = adj[idx] + ((i == j) ? 1.f : 0.f);
    An[idx] = dg[b * 256 + i] * v * dg[b * 256 + j];
}

// ---- naive GEMM kept only for K=6 (x@W1) ----
__global__ void k_mm(const float* A, const float* B, float* C,
                     int M, int K, int N) {
    int idx = blockIdx.x * 256 + threadIdx.x;
    if (idx >= M * N) return;
    int n = idx % N, m = idx / N;
    float s = 0.f;
    for (int k = 0; k < K; k++) s += A[m * K + k] * B[k * N + n];
    C[idx] = s;
}

// ---- tiled GEMM: C = A@B [+bias][relu], optional A-affine (BN+relu) ----
// 32x32 tile, 256 threads, 2x2 per thread; 1-D grid = tiles_n*tiles_m*batch
__global__ void k_tgemm(const float* A, const float* B, const float* bias,
                        const float* aff, float* C,
                        int M, int K, int N, int relu,
                        int sA, int sB, int sC, int tiles_n, int tiles_m) {
    __shared__ float As[16][33];
    __shared__ float Bs[16][33];
    int tid = threadIdx.x;
    int tx = tid & 15, ty = tid >> 4;
    int bx = blockIdx.x % tiles_n;
    int tmp = blockIdx.x / tiles_n;
    int by = tmp % tiles_m;
    int bz = tmp / tiles_m;
    int m0 = by * 32, n0 = bx * 32;
    const float* Ab = A + (long)bz * sA;
    const float* Bb = B + (long)bz * sB;
    float* Cb = C + (long)bz * sC;
    float c00 = 0.f, c01 = 0.f, c10 = 0.f, c11 = 0.f;
    for (int k0 = 0; k0 < K; k0 += 16) {
        for (int l = 0; l < 2; l++) {
            int idx = tid + l * 256;
            int kk = idx & 15, mm = idx >> 4;        // A: coalesced along K
            int kg = k0 + kk;
            float v = 0.f;
            if (kg < K) {
                v = Ab[(m0 + mm) * K + kg];
                if (aff != 0) {
                    v = v * aff[kg] + aff[K + kg];
                    if (v < 0.f) v = 0.f;
                }
            }
            As[kk][mm] = v;
            int nn2 = idx & 31, kk2 = idx >> 5;      // B: coalesced along N
            int kg2 = k0 + kk2, ng = n0 + nn2;
            float w = 0.f;
            if (kg2 < K && ng < N) w = Bb[kg2 * N + ng];
            Bs[kk2][nn2] = w;
        }
        __syncthreads();
        #pragma unroll
        for (int kk = 0; kk < 16; kk++) {
            float A0 = As[kk][ty * 2], A1 = As[kk][ty * 2 + 1];
            float B0 = Bs[kk][tx * 2], B1 = Bs[kk][tx * 2 + 1];
            c00 += A0 * B0; c01 += A0 * B1; c10 += A1 * B0; c11 += A1 * B1;
        }
        __syncthreads();
    }
    int mm = m0 + ty * 2, nn = n0 + tx * 2;
    float r00 = c00, r01 = c01, r10 = c10, r11 = c11;
    if (bias != 0) {
        float bq0 = bias[nn], bq1 = bias[nn + 1];
        r00 += bq0; r01 += bq1; r10 += bq0; r11 += bq1;
    }
    if (relu) {
        if (r00 < 0.f) r00 = 0.f;
        if (r01 < 0.f) r01 = 0.f;
        if (r10 < 0.f) r10 = 0.f;
        if (r11 < 0.f) r11 = 0.f;
    }
    Cb[(long)mm * N + nn] = r00;
    Cb[(long)mm * N + nn + 1] = r01;
    Cb[(long)(mm + 1) * N + nn] = r10;
    Cb[(long)(mm + 1) * N + nn + 1] = r11;
}

// ---- BN stats over (1024,128) -> fused affine: st[c]=scale, st[128+c]=shift ----
__global__ void k_bn_stats(const float* pre, const float* g, const float* beta,
                           float* st) {
    __shared__ float ss[256];
    __shared__ float qq[256];
    int c = blockIdx.x;        // 128 blocks
    int t = threadIdx.x;
    float s = 0.f, q = 0.f;
    for (int r = t; r < 1024; r += 256) {
        float v = pre[r * 128 + c];
        s += v; q += v * v;
    }
    ss[t] = s; qq[t] = q;
    __syncthreads();
    for (int o = 128; o > 0; o >>= 1) {
        if (t < o) { ss[t] += ss[t + o]; qq[t] += qq[t + o]; }
        __syncthreads();
    }
    if (t == 0) {
        float mu  = ss[0] * (1.f / 1024.f);
        float var = qq[0] * (1.f / 1024.f) - mu * mu;
        float rstd = rsqrtf(var + 1e-5f);
        float sc = rstd * g[c];
        st[c] = sc;
        st[128 + c] = beta[c] - mu * sc;
    }
}

// ---- hjT[b][k][j] = hj[b][j][k] ----
__global__ void k_transp(const float* hj, float* hjT) {
    int idx = blockIdx.x * 256 + threadIdx.x;   // 131072
    int b = idx >> 15;
    int r = idx & 32767;
    int k = r >> 8;
    int j = r & 255;
    hjT[idx] = hj[(b * 256 + j) * 128 + k];
}

// ---- pairwise decoder ----
// block=(b,i), thread=j. 2 passes x 32 named register accumulators.
// weights read from global with wave-uniform addresses (scalarizable).
#define DEC_ACC(OP) OP(0) OP(1) OP(2) OP(3) OP(4) OP(5) OP(6) OP(7) \
    OP(8) OP(9) OP(10) OP(11) OP(12) OP(13) OP(14) OP(15) \
    OP(16) OP(17) OP(18) OP(19) OP(20) OP(21) OP(22) OP(23) \
    OP(24) OP(25) OP(26) OP(27) OP(28) OP(29) OP(30) OP(31)

__global__ void k_dec(const float* hi, const float* hjT, const float* e1b,
                      const float* e2w, const float* e2b,
                      const float* e3w, const float* e3b, float* lgt) {
    __shared__ float pre[128];
    int tid = threadIdx.x;
    int bi = blockIdx.x, b = bi >> 8;
    if (tid < 128) pre[tid] = hi[bi * 128 + tid] + e1b[tid];
    __syncthreads();
    const float* hp = hjT + b * 32768 + tid;    // [k][j], coalesced per k
    float s = e3b[0];
    for (int pass = 0; pass < 2; pass++) {
        const float* w = e2w + pass * 32;
#define DECL(i) float a##i = 0.f;
        DEC_ACC(DECL)
#undef DECL
        for (int k = 0; k < 128; k++) {
            float p = pre[k] + hp[k * 256];
            p = (p > 0.f) ? p : 0.f;
            const float* wk = w + k * 64;
#define FMA(i) a##i += p * wk[i];
            DEC_ACC(FMA)
#undef FMA
        }
        const float* eb = e2b + pass * 32;
        const float* ew = e3w + pass * 32;
        float v;
#define EPI(i) v = a##i + eb[i]; if (v > 0.f) s += v * ew[i];
        DEC_ACC(EPI)
#undef EPI
    }
    lgt[bi * 256 + tid] = s;
}

// ---- symmetrize + sigmoid ----
__global__ void k_symsig(const float* lgt, float* out) {
    int idx = blockIdx.x * 256 + threadIdx.x;   // 262144
    int b = idx >> 16, i = (idx >> 8) & 255, j = idx & 255;
    float v = 0.5f * (lgt[idx] + lgt[(b << 16) + (j << 8) + i]);
    out[idx] = 1.f / (1.f + expf(-v));
}

// ---- feat decoder last layer: (1024x128)@(128x6)+b ----
__global__ void k_f3(const float* f2, const float* w, const float* bias,
                     float* out) {
    int idx = blockIdx.x * 256 + threadIdx.x;   // 6144
    if (idx >= 6144) return;
    int r = idx / 6, c = idx % 6;
    float s = bias[c];
    for (int k = 0; k < 128; k++) s += f2[r * 128 + k] * w[k * 6 + c];
    out[idx] = s;
}

extern "C" void kernel_launch(void* const* d_in, const int* in_sizes, int n_in,
                              void* d_out, int out_size, void* d_ws, size_t ws_size,
                              hipStream_t stream) {
    const float* x   = (const float*)d_in[0];
    const float* adj = (const float*)d_in[1];
    const float* W1  = (const float*)d_in[2];
    const float* b1  = (const float*)d_in[3];
    const float* W2  = (const float*)d_in[4];
    const float* b2  = (const float*)d_in[5];
    const float* W3  = (const float*)d_in[6];
    const float* b3  = (const float*)d_in[7];
    const float* g1  = (const float*)d_in[8];
    const float* be1 = (const float*)d_in[9];
    const float* g2  = (const float*)d_in[10];
    const float* be2 = (const float*)d_in[11];
    const float* e1w = (const float*)d_in[12];
    const float* e1b = (const float*)d_in[13];
    const float* e2w = (const float*)d_in[14];
    const float* e2b = (const float*)d_in[15];
    const float* e3w = (const float*)d_in[16];
    const float* e3b = (const float*)d_in[17];
    const float* f1w = (const float*)d_in[18];
    const float* f1b = (const float*)d_in[19];
    const float* f2w = (const float*)d_in[20];
    const float* f2b_ = (const float*)d_in[21];
    const float* f3w = (const float*)d_in[22];
    const float* f3b = (const float*)d_in[23];

    float* out = (float*)d_out;

    // workspace: 1,705,216 floats (~6.8 MB)
    if (ws_size < (size_t)1705216 * 4) {
        hipMemsetAsync(d_out, 0x60, 4096, stream);   // diagnostic
        return;
    }
    float* cur = (float*)d_ws;
    float* An  = cur; cur += 262144;
    float* buf = cur; cur += 262144;
    float* hb  = cur; cur += 262144;
    float* lg  = cur; cur += 262144;
    float* h1  = cur; cur += 131072;
    float* h2  = cur; cur += 131072;
    float* hi  = cur; cur += 131072;
    float* hj  = cur; cur += 131072;   // must follow hi (batch-2 GEMM writes both)
    float* hjT = cur; cur += 131072;
    float* st  = cur; cur += 256;
    float* dg  = cur; cur += 1024;

    k_deg<<<1024, 256, 0, stream>>>(adj, dg);
    k_an<<<1024, 256, 0, stream>>>(adj, dg, An);

    // layer 1: buf = x@W1 ; h1 = An@buf + b1 ; BN stats (fused apply downstream)
    k_mm<<<512, 256, 0, stream>>>(x, W1, buf, 1024, 6, 128);
    k_tgemm<<<128, 256, 0, stream>>>(An, buf, b1, 0, h1, 256, 256, 128, 0,
                                     65536, 32768, 32768, 4, 8);
    k_bn_stats<<<128, 256, 0, stream>>>(h1, g1, be1, st);

    // layer 2: buf = BN(h1)@W2 ; h2 = An@buf + b2 ; BN stats
    k_tgemm<<<128, 256, 0, stream>>>(h1, W2, 0, st, buf, 1024, 128, 128, 0,
                                     0, 0, 0, 4, 32);
    k_tgemm<<<128, 256, 0, stream>>>(An, buf, b2, 0, h2, 256, 256, 128, 0,
                                     65536, 32768, 32768, 4, 8);
    k_bn_stats<<<128, 256, 0, stream>>>(h2, g2, be2, st);

    // layer 3: buf = BN(h2)@W3 ; hb = relu(An@buf + b3)
    k_tgemm<<<256, 256, 0, stream>>>(h2, W3, 0, st, buf, 1024, 128, 256, 0,
                                     0, 0, 0, 8, 32);
    k_tgemm<<<256, 256, 0, stream>>>(An, buf, b3, 0, hb, 256, 256, 256, 1,
                                     65536, 65536, 65536, 8, 8);

    // adjacency decoder: hi = hb@e1w[:256], hj = hb@e1w[256:]  (batch-2, sA=0)
    k_tgemm<<<256, 256, 0, stream>>>(hb, e1w, 0, 0, hi, 1024, 256, 128, 0,
                                     0, 32768, 131072, 4, 32);
    k_transp<<<512, 256, 0, stream>>>(hj, hjT);
    k_dec<<<1024, 256, 0, stream>>>(hi, hjT, e1b, e2w, e2b, e3w, e3b, lg);
    k_symsig<<<1024, 256, 0, stream>>>(lg, out);

    // feature decoder
    k_tgemm<<<128, 256, 0, stream>>>(hb, f1w, f1b, 0, h1, 1024, 256, 128, 1,
                                     0, 0, 0, 4, 32);
    k_tgemm<<<128, 256, 0, stream>>>(h1, f2w, f2b_, 0, h2, 1024, 128, 128, 1,
                                     0, 0, 0, 4, 32);
    k_f3<<<24, 256, 0, stream>>>(h2, f3w, f3b, out + 262144);
}

// Round 8
// 281.353 us; speedup vs baseline: 2.9748x; 1.2350x over previous
//
#include <hip/hip_runtime.h>

// Shapes (fixed): B=4, N=256, F=6, H=128, D=256, B*N=1024
// All tensors fp32. out = concat(adj_pred [4,256,256], feat_pred [4,256,6]).

typedef float v4f __attribute__((ext_vector_type(4)));
typedef short v8s __attribute__((ext_vector_type(8)));

__device__ __forceinline__ unsigned short f2bs(float f) {
    union { float f; unsigned int u; } v;
    v.f = f;
    return (unsigned short)((v.u + 0x7fffu + ((v.u >> 16) & 1u)) >> 16);
}

// ---- degree: block per row, LDS tree reduction ----
__global__ void k_deg(const float* adj, float* dg) {
    __shared__ float ss[256];
    int row = blockIdx.x;            // 1024
    int t = threadIdx.x;
    ss[t] = adj[row * 256 + t];
    __syncthreads();
    for (int o = 128; o > 0; o >>= 1) {
        if (t < o) ss[t] += ss[t + o];
        __syncthreads();
    }
    if (t == 0) {
        float s = ss[0] + 1.f;
        if (s < 1.f) s = 1.f;
        dg[row] = rsqrtf(s);
    }
}

// ---- An[b,i,j] = d_i * (adj + I) * d_j ----
__global__ void k_an(const float* adj, const float* dg, float* An) {
    int idx = blockIdx.x * 256 + threadIdx.x;   // 262144
    int b = idx >> 16, i = (idx >> 8) & 255, j = idx & 255;
    float v = adj[idx] + ((i == j) ? 1.f : 0.f);
    An[idx] = dg[b * 256 + i] * v * dg[b * 256 + j];
}

// ---- naive GEMM kept only for K=6 (x@W1) ----
__global__ void k_mm(const float* A, const float* B, float* C,
                     int M, int K, int N) {
    int idx = blockIdx.x * 256 + threadIdx.x;
    if (idx >= M * N) return;
    int n = idx % N, m = idx / N;
    float s = 0.f;
    for (int k = 0; k < K; k++) s += A[m * K + k] * B[k * N + n];
    C[idx] = s;
}

// ---- tiled GEMM: C = A@B [+bias][relu]
//  consumer-BN: if (stat) A-element gets BN affine from raw sum/sumsq + g/beta
//  producer-BN: if (ostat) per-column sum/sumsq of C atomically accumulated
// 32x32 tile, 256 threads, 2x2 per thread; 1-D grid = tiles_n*tiles_m*batch
__global__ void k_tgemm(const float* A, const float* B, const float* bias,
                        const float* stat, const float* g, const float* beta,
                        float* ostat, float* C,
                        int M, int K, int N, int relu,
                        int sA, int sB, int sC, int tiles_n, int tiles_m) {
    __shared__ float As[16][33];
    __shared__ float Bs[16][33];
    int tid = threadIdx.x;
    int tx = tid & 15, ty = tid >> 4;
    int bx = blockIdx.x % tiles_n;
    int tmp = blockIdx.x / tiles_n;
    int by = tmp % tiles_m;
    int bz = tmp / tiles_m;
    int m0 = by * 32, n0 = bx * 32;
    const float* Ab = A + (long)bz * sA;
    const float* Bb = B + (long)bz * sB;
    float* Cb = C + (long)bz * sC;
    float c00 = 0.f, c01 = 0.f, c10 = 0.f, c11 = 0.f;
    for (int k0 = 0; k0 < K; k0 += 16) {
        for (int l = 0; l < 2; l++) {
            int idx = tid + l * 256;
            int kk = idx & 15, mm = idx >> 4;        // A: coalesced along K
            int kg = k0 + kk;
            float v = 0.f;
            if (kg < K) {
                v = Ab[(m0 + mm) * K + kg];
                if (stat != 0) {                     // BN affine + relu on A
                    float mu = stat[kg] * (1.f / 1024.f);
                    float vr = stat[128 + kg] * (1.f / 1024.f) - mu * mu;
                    float sc = rsqrtf(vr + 1e-5f) * g[kg];
                    v = (v - mu) * sc + beta[kg];
                    if (v < 0.f) v = 0.f;
                }
            }
            As[kk][mm] = v;
            int nn2 = idx & 31, kk2 = idx >> 5;      // B: coalesced along N
            int kg2 = k0 + kk2, ng = n0 + nn2;
            float w = 0.f;
            if (kg2 < K && ng < N) w = Bb[kg2 * N + ng];
            Bs[kk2][nn2] = w;
        }
        __syncthreads();
        #pragma unroll
        for (int kk = 0; kk < 16; kk++) {
            float A0 = As[kk][ty * 2], A1 = As[kk][ty * 2 + 1];
            float B0 = Bs[kk][tx * 2], B1 = Bs[kk][tx * 2 + 1];
            c00 += A0 * B0; c01 += A0 * B1; c10 += A1 * B0; c11 += A1 * B1;
        }
        __syncthreads();
    }
    int mm = m0 + ty * 2, nn = n0 + tx * 2;
    float r00 = c00, r01 = c01, r10 = c10, r11 = c11;
    if (bias != 0) {
        float bq0 = bias[nn], bq1 = bias[nn + 1];
        r00 += bq0; r01 += bq1; r10 += bq0; r11 += bq1;
    }
    if (relu) {
        if (r00 < 0.f) r00 = 0.f;
        if (r01 < 0.f) r01 = 0.f;
        if (r10 < 0.f) r10 = 0.f;
        if (r11 < 0.f) r11 = 0.f;
    }
    Cb[(long)mm * N + nn] = r00;
    Cb[(long)mm * N + nn + 1] = r01;
    Cb[(long)(mm + 1) * N + nn] = r10;
    Cb[(long)(mm + 1) * N + nn + 1] = r11;

    if (ostat != 0) {                                // column stats of C tile
        float* sred = &As[0][0];
        float* qred = &Bs[0][0];
        __syncthreads();
        sred[(tx * 2 + 0) * 16 + ty] = r00 + r10;
        qred[(tx * 2 + 0) * 16 + ty] = r00 * r00 + r10 * r10;
        sred[(tx * 2 + 1) * 16 + ty] = r01 + r11;
        qred[(tx * 2 + 1) * 16 + ty] = r01 * r01 + r11 * r11;
        __syncthreads();
        if (tid < 32) {
            float s = 0.f, q = 0.f;
            for (int u = 0; u < 16; u++) {
                s += sred[tid * 16 + u];
                q += qred[tid * 16 + u];
            }
            atomicAdd(&ostat[n0 + tid], s);
            atomicAdd(&ostat[128 + n0 + tid], q);
        }
    }
}

// ---- pairwise decoder via MFMA bf16 ----
// block=(b,i): P(256x128)=relu(pre+hj) @ e2w(128x64) -> relu(+e2b) dot e3w
__global__ void k_dec(const float* hi, const float* hj, const float* e1b,
                      const float* e2w, const float* e2b,
                      const float* e3w, const float* e3b, float* lgt) {
    __shared__ unsigned short bfr[8192];   // e2w as bf16 in B-frag layout
    __shared__ float pre_sh[128];
    __shared__ float red[4096];
    int tid = threadIdx.x;
    int bi = blockIdx.x, b = bi >> 8;
    int lane = tid & 63, wv = tid >> 6;
    int col = lane & 15, quad = lane >> 4;

    // stage e2w -> bfr: coalesced global reads, scattered LDS writes
    for (int s = tid; s < 1024; s += 256) {
        int base = s * 8;                 // linear e2w index, 8 consecutive n
        int k = base >> 6;
        int n0 = base & 63;
        int kc = k >> 5, q = (k & 31) >> 3, t = k & 7;
        for (int u = 0; u < 8; u++) {
            int n = n0 + u;
            int nt = n >> 4, c2 = n & 15;
            bfr[(((nt * 4 + kc) * 64) + q * 16 + c2) * 8 + t] = f2bs(e2w[base + u]);
        }
    }
    if (tid < 128) pre_sh[tid] = hi[bi * 128 + tid] + e1b[tid];
    __syncthreads();

    float preR[4][8];
    for (int kc = 0; kc < 4; kc++)
        for (int t = 0; t < 8; t++) preR[kc][t] = pre_sh[kc * 32 + quad * 8 + t];

    v4f acc[4][4];
    for (int ms = 0; ms < 4; ms++)
        for (int nt = 0; nt < 4; nt++) {
            v4f z = {0.f, 0.f, 0.f, 0.f};
            acc[ms][nt] = z;
        }

    const float* hjb = hj + b * 32768;    // [j][k], row-major
    for (int kc = 0; kc < 4; kc++) {
        v8s bfrag[4];
        for (int nt = 0; nt < 4; nt++)
            bfrag[nt] = *(const v8s*)&bfr[(((nt * 4 + kc) * 64) + lane) * 8];
        for (int ms = 0; ms < 4; ms++) {
            int j = wv * 64 + ms * 16 + col;         // A row m = lane&15
            const float* hp = hjb + j * 128 + kc * 32 + quad * 8;
            v8s af;
            for (int t = 0; t < 8; t++) {
                float p = preR[kc][t] + hp[t];
                p = (p > 0.f) ? p : 0.f;
                af[t] = (short)f2bs(p);
            }
            for (int nt = 0; nt < 4; nt++)
                acc[ms][nt] = __builtin_amdgcn_mfma_f32_16x16x32_bf16(
                    af, bfrag[nt], acc[ms][nt], 0, 0, 0);
        }
    }

    // epilogue: per lane, partial over its column; reduce 16 cols via LDS
    float e2bv[4], e3wv[4];
    for (int nt = 0; nt < 4; nt++) {
        e2bv[nt] = e2b[nt * 16 + col];
        e3wv[nt] = e3w[nt * 16 + col];
    }
    for (int ms = 0; ms < 4; ms++) {
        for (int r = 0; r < 4; r++) {
            float s = 0.f;
            for (int nt = 0; nt < 4; nt++) {
                float v = acc[ms][nt][r] + e2bv[nt];
                if (v > 0.f) s += v * e3wv[nt];
            }
            // C/D layout: row = quad*4 + r, col = lane&15
            red[wv * 1024 + (ms * 16 + quad * 4 + r) * 16 + col] = s;
        }
    }
    __syncthreads();
    float s = e3b[0];
    for (int c = 0; c < 16; c++) s += red[tid * 16 + c];
    lgt[bi * 256 + tid] = s;
}

// ---- symmetrize + sigmoid ----
__global__ void k_symsig(const float* lgt, float* out) {
    int idx = blockIdx.x * 256 + threadIdx.x;   // 262144
    int b = idx >> 16, i = (idx >> 8) & 255, j = idx & 255;
    float v = 0.5f * (lgt[idx] + lgt[(b << 16) + (j << 8) + i]);
    out[idx] = 1.f / (1.f + expf(-v));
}

// ---- feat decoder last layer: (1024x128)@(128x6)+b ----
__global__ void k_f3(const float* f2, const float* w, const float* bias,
                     float* out) {
    int idx = blockIdx.x * 256 + threadIdx.x;   // 6144
    if (idx >= 6144) return;
    int r = idx / 6, c = idx % 6;
    float s = bias[c];
    for (int k = 0; k < 128; k++) s += f2[r * 128 + k] * w[k * 6 + c];
    out[idx] = s;
}

extern "C" void kernel_launch(void* const* d_in, const int* in_sizes, int n_in,
                              void* d_out, int out_size, void* d_ws, size_t ws_size,
                              hipStream_t stream) {
    const float* x   = (const float*)d_in[0];
    const float* adj = (const float*)d_in[1];
    const float* W1  = (const float*)d_in[2];
    const float* b1  = (const float*)d_in[3];
    const float* W2  = (const float*)d_in[4];
    const float* b2  = (const float*)d_in[5];
    const float* W3  = (const float*)d_in[6];
    const float* b3  = (const float*)d_in[7];
    const float* g1  = (const float*)d_in[8];
    const float* be1 = (const float*)d_in[9];
    const float* g2  = (const float*)d_in[10];
    const float* be2 = (const float*)d_in[11];
    const float* e1w = (const float*)d_in[12];
    const float* e1b = (const float*)d_in[13];
    const float* e2w = (const float*)d_in[14];
    const float* e2b = (const float*)d_in[15];
    const float* e3w = (const float*)d_in[16];
    const float* e3b = (const float*)d_in[17];
    const float* f1w = (const float*)d_in[18];
    const float* f1b = (const float*)d_in[19];
    const float* f2w = (const float*)d_in[20];
    const float* f2b_ = (const float*)d_in[21];
    const float* f3w = (const float*)d_in[22];
    const float* f3b = (const float*)d_in[23];

    float* out = (float*)d_out;

    // workspace: ~1,575,000 floats (~6.3 MB)
    if (ws_size < (size_t)1575000 * 4) {
        hipMemsetAsync(d_out, 0x60, 4096, stream);   // diagnostic
        return;
    }
    float* cur = (float*)d_ws;
    float* An  = cur; cur += 262144;
    float* buf = cur; cur += 262144;
    float* hb  = cur; cur += 262144;
    float* lg  = cur; cur += 262144;
    float* h1  = cur; cur += 131072;
    float* h2  = cur; cur += 131072;
    float* hi  = cur; cur += 131072;
    float* hj  = cur; cur += 131072;   // must follow hi (batch-2 GEMM writes both)
    float* st1 = cur; cur += 256;      // [0:128) sum, [128:256) sumsq of h1
    float* st2 = cur; cur += 256;      // same for h2
    float* dg  = cur; cur += 1024;

    hipMemsetAsync(st1, 0, 512 * sizeof(float), stream);   // zero st1+st2

    k_deg<<<1024, 256, 0, stream>>>(adj, dg);
    k_an<<<1024, 256, 0, stream>>>(adj, dg, An);

    // layer 1: buf = x@W1 ; h1 = An@buf + b1 (+ column stats -> st1)
    k_mm<<<512, 256, 0, stream>>>(x, W1, buf, 1024, 6, 128);
    k_tgemm<<<128, 256, 0, stream>>>(An, buf, b1, 0, 0, 0, st1, h1,
                                     256, 256, 128, 0, 65536, 32768, 32768, 4, 8);

    // layer 2: buf = BN(h1)@W2 ; h2 = An@buf + b2 (+ stats -> st2)
    k_tgemm<<<128, 256, 0, stream>>>(h1, W2, 0, st1, g1, be1, 0, buf,
                                     1024, 128, 128, 0, 0, 0, 0, 4, 32);
    k_tgemm<<<128, 256, 0, stream>>>(An, buf, b2, 0, 0, 0, st2, h2,
                                     256, 256, 128, 0, 65536, 32768, 32768, 4, 8);

    // layer 3: buf = BN(h2)@W3 ; hb = relu(An@buf + b3)
    k_tgemm<<<256, 256, 0, stream>>>(h2, W3, 0, st2, g2, be2, 0, buf,
                                     1024, 128, 256, 0, 0, 0, 0, 8, 32);
    k_tgemm<<<256, 256, 0, stream>>>(An, buf, b3, 0, 0, 0, 0, hb,
                                     256, 256, 256, 1, 65536, 65536, 65536, 8, 8);

    // adjacency decoder: hi = hb@e1w[:256], hj = hb@e1w[256:]  (batch-2, sA=0)
    k_tgemm<<<256, 256, 0, stream>>>(hb, e1w, 0, 0, 0, 0, 0, hi,
                                     1024, 256, 128, 0, 0, 32768, 131072, 4, 32);
    k_dec<<<1024, 256, 0, stream>>>(hi, hj, e1b, e2w, e2b, e3w, e3b, lg);
    k_symsig<<<1024, 256, 0, stream>>>(lg, out);

    // feature decoder
    k_tgemm<<<128, 256, 0, stream>>>(hb, f1w, f1b, 0, 0, 0, 0, h1,
                                     1024, 256, 128, 1, 0, 0, 0, 4, 32);
    k_tgemm<<<128, 256, 0, stream>>>(h1, f2w, f2b_, 0, 0, 0, 0, h2,
                                     1024, 128, 128, 1, 0, 0, 0, 4, 32);
    k_f3<<<24, 256, 0, stream>>>(h2, f3w, f3b, out + 262144);
}